// Round 11
// baseline (155.054 us; speedup 1.0000x reference)
//
#include <hip/hip_runtime.h>

typedef __attribute__((ext_vector_type(8))) short short8;
typedef __attribute__((ext_vector_type(4))) float f32x4;
typedef unsigned short u16;

#define BB 4
#define TT 4096
#define CC 1024
#define HH 64

static __device__ __forceinline__ u16 f2bf(float f) {
    unsigned int u = __float_as_uint(f);
    unsigned int r = (u + 0x7FFFu + ((u >> 16) & 1u)) >> 16;  // RNE
    return (u16)r;
}

// pack 2 f32 -> 2 bf16 in one u32 (lo = first arg); no builtin on gfx950 (T12)
static __device__ __forceinline__ unsigned int cvtpk(float lo, float hi) {
    unsigned int r;
    asm("v_cvt_pk_bf16_f32 %0, %1, %2" : "=v"(r) : "v"(lo), "v"(hi));
    return r;
}

// attn LDS tile addressing: 64-u16 rows, 8 chunks of 8 u16; chunk XOR-swizzled by row&7.
static __device__ __forceinline__ int swz(int row, int chunk) {
    return row * 64 + ((chunk ^ (row & 7)) << 3);
}

static __device__ __forceinline__ int probe_isbf(const u16* xu, int tid) {
    int lane = tid & 63;
    int cnt = 0;
    for (int i = lane; i < 1024; i += 64) {
        u16 u = xu[2 * i];
        int e = (u >> 7) & 0xFF;
        cnt += (e >= 100 && e <= 140) ? 1 : 0;
    }
    for (int d = 1; d < 64; d <<= 1) cnt += __shfl_xor(cnt, d);
    return (cnt > 512) ? 1 : 0;
}

// ---------------- prep: dtype probe + W -> Wtp packed B-fragment order.
// 192 blocks; block 0 additionally publishes the dtype flag.
__global__ void prep(const void* __restrict__ Wk, const void* __restrict__ Wq,
                     const void* __restrict__ Wv, const u16* __restrict__ xu,
                     u16* __restrict__ Wtp, int* __restrict__ flag) {
    __shared__ int sflag;
    if (threadIdx.x < 64) {
        int f = probe_isbf(xu, threadIdx.x);
        if (threadIdx.x == 0) sflag = f;
    }
    __syncthreads();
    const int isbf = sflag;
    if (blockIdx.x == 0 && threadIdx.x == 0) *flag = isbf;

    int r = blockIdx.x;          // global output col 0..191
    int p = r >> 6;              // 0=q 1=k 2=v
    int n = r & 63;
    int nt = n >> 4, nl = n & 15;
    const void* W = (p == 0) ? Wq : (p == 1) ? Wk : Wv;
    int k0 = threadIdx.x * 4;    // 4 consecutive k per thread
    int kb = k0 >> 6, k2 = (k0 >> 5) & 1, quad = (k0 >> 3) & 3, half = (k0 >> 2) & 1;
    ushort4 v;
    if (isbf) {
        const u16* Wb = (const u16*)W;
        v.x = Wb[(k0 + 0) * HH + n]; v.y = Wb[(k0 + 1) * HH + n];
        v.z = Wb[(k0 + 2) * HH + n]; v.w = Wb[(k0 + 3) * HH + n];
    } else {
        const float* Wf = (const float*)W;
        v.x = f2bf(Wf[(k0 + 0) * HH + n]); v.y = f2bf(Wf[(k0 + 1) * HH + n]);
        v.z = f2bf(Wf[(k0 + 2) * HH + n]); v.w = f2bf(Wf[(k0 + 3) * HH + n]);
    }
    size_t off16 = ((size_t)((p * 4 + nt) * 16 + kb) * 2 + k2) * 64 + quad * 16 + nl;
    *reinterpret_cast<ushort4*>(Wtp + off16 * 8 + half * 4) = v;
}

// ---------------- QKV projection v5 (R6 form): 32 rows/block, fused LDS transpose,
// one barrier; compiler handles Wtp load pipelining.
__global__ __launch_bounds__(256) void qkv_proj(const void* __restrict__ x,
                                                const u16* __restrict__ Wtp,
                                                u16* __restrict__ qo, u16* __restrict__ ko,
                                                u16* __restrict__ vo, const int* __restrict__ flag) {
    __shared__ __align__(16) u16 xs[32 * 1024];   // [row][k], 16B chunks swizzled by row&7
    __shared__ __align__(16) u16 tls[4][3][256];  // per-wave, per-proj 16x16 transpose tile
    const int isbf = *flag;
    const int tid = threadIdx.x;
    const int lane = tid & 63;
    const int w = tid >> 6;
    const int l15 = lane & 15;
    const int quad = lane >> 4;
    int phys = blockIdx.x;
    int rb = (phys & 7) * 64 + (phys >> 3);       // XCD-affine 32-row group, 0..511
    const int g0r = rb * 32;

    // ---- stage 32 rows of x (contiguous reads; swizzled 16B-chunk writes)
    #pragma unroll
    for (int j = 0; j < 16; j++) {
        int c = tid + j * 256;                    // 4096 chunks: row = c>>7, ck = c&127
        int row = c >> 7, ck = c & 127;
        int dst = row * 1024 + ((ck ^ (row & 7)) << 3);
        if (isbf) {
            uint4 d = *reinterpret_cast<const uint4*>((const u16*)x + (size_t)(g0r + row) * CC + ck * 8);
            *reinterpret_cast<uint4*>(xs + dst) = d;
        } else {
            const float4* pf = reinterpret_cast<const float4*>((const float*)x + (size_t)(g0r + row) * CC + ck * 8);
            float4 a0 = pf[0], a1 = pf[1];
            ushort4 lo; lo.x = f2bf(a0.x); lo.y = f2bf(a0.y); lo.z = f2bf(a0.z); lo.w = f2bf(a0.w);
            ushort4 hi; hi.x = f2bf(a1.x); hi.y = f2bf(a1.y); hi.z = f2bf(a1.z); hi.w = f2bf(a1.w);
            *reinterpret_cast<ushort4*>(xs + dst) = lo;
            *reinterpret_cast<ushort4*>(xs + dst + 4) = hi;
        }
    }
    __syncthreads();                              // the ONLY block-wide barrier

    f32x4 zero = {0.f, 0.f, 0.f, 0.f};
    f32x4 acc[3][2];                              // [proj][row-tile]
    #pragma unroll
    for (int i = 0; i < 3; i++) { acc[i][0] = zero; acc[i][1] = zero; }

    for (int kb = 0; kb < 16; kb++) {
        #pragma unroll
        for (int k2 = 0; k2 < 2; k2++) {
            int ck = kb * 8 + k2 * 4 + quad;
            int xo = ((ck ^ (l15 & 7)) << 3);
            short8 af0 = *reinterpret_cast<const short8*>(xs + l15 * 1024 + xo);
            short8 af1 = *reinterpret_cast<const short8*>(xs + (16 + l15) * 1024 + xo);
            #pragma unroll
            for (int p = 0; p < 3; p++) {
                short8 bf = *reinterpret_cast<const short8*>(
                    Wtp + ((((size_t)(p * 4 + w) * 16 + kb) * 2 + k2) * 64 + lane) * 8);
                acc[p][0] = __builtin_amdgcn_mfma_f32_16x16x32_bf16(af0, bf, acc[p][0], 0, 0, 0);
                acc[p][1] = __builtin_amdgcn_mfma_f32_16x16x32_bf16(af1, bf, acc[p][1], 0, 0, 0);
            }
        }
    }

    // ---- epilogue per row-tile: per-wave 16x16 LDS transpose, 8B coalesced stores
    const float qscale = 0.18033688011112042f;    // log2(e)/8
    #pragma unroll
    for (int rt = 0; rt < 2; rt++) {
        const int g0rt = g0r + rt * 16;
        #pragma unroll
        for (int p = 0; p < 3; p++) {
            if (p < 2) {
                float sc = (p == 0) ? qscale : 1.f;
                #pragma unroll
                for (int r = 0; r < 4; r++)       // [t(16)][c(16)]
                    tls[w][p][(quad * 4 + r) * 16 + l15] = f2bf(acc[p][rt][r] * sc);
            } else {
                #pragma unroll
                for (int r = 0; r < 4; r++)       // [c(16)][t(16)]
                    tls[w][p][l15 * 16 + quad * 4 + r] = f2bf(acc[p][rt][r]);
            }
        }
        // same-wave LDS RAW: compiler inserts lgkmcnt wait; no barrier needed
        #pragma unroll
        for (int p = 0; p < 2; p++) {             // q, k: row-major (g0rt+t)*64 + w*16+c
            int t = lane >> 2, seg = lane & 3;
            ushort4 d = *reinterpret_cast<const ushort4*>(&tls[w][p][t * 16 + seg * 4]);
            u16* dst = (p == 0) ? qo : ko;
            *reinterpret_cast<ushort4*>(dst + (size_t)(g0rt + t) * HH + w * 16 + seg * 4) = d;
        }
        {                                         // v: vo[b][kt][h][64keys]
            int c = lane >> 2, seg = lane & 3;
            ushort4 d = *reinterpret_cast<const ushort4*>(&tls[w][2][c * 16 + seg * 4]);
            int b = g0rt >> 12;
            int kt = (g0rt & 4095) >> 6;
            int toff = g0rt & 63;
            *reinterpret_cast<ushort4*>(vo + ((size_t)((b * 64 + kt) * 64 + w * 16 + c)) * 64 + toff + seg * 4) = d;
        }
    }
}

// QK^T from register K fragments (kf[k2*4+nt]); S^T = mfma(K, Q)
static __device__ __forceinline__ void qkt_regs(const short8* kf, const short8* aq, f32x4* s) {
    __builtin_amdgcn_s_setprio(1);
    #pragma unroll
    for (int k2 = 0; k2 < 2; k2++) {
        #pragma unroll
        for (int nt = 0; nt < 4; nt++)
            s[nt] = __builtin_amdgcn_mfma_f32_16x16x32_bf16(kf[k2 * 4 + nt], aq[k2], s[nt], 0, 0, 0);
    }
    __builtin_amdgcn_s_setprio(0);
}

// load the 8 K fragments for tile kt directly from global (wave-uniform across w:
// wave 0 misses to L2, waves 1-3 hit L1 on the identical addresses)
static __device__ __forceinline__ void load_kf(short8* kf, const u16* kfb, size_t toff) {
    #pragma unroll
    for (int k2 = 0; k2 < 2; k2++) {
        #pragma unroll
        for (int nt = 0; nt < 4; nt++)
            kf[k2 * 4 + nt] = *reinterpret_cast<const short8*>(kfb + toff + nt * 1024 + k2 * 32);
    }
}

// softmax + P staging + PV for one q-tile on one staged V tile (S^T form)
static __device__ __forceinline__ void smpv(f32x4* s, const u16* __restrict__ vtsc,
                                            u16* __restrict__ pbw, f32x4* o, float& lsum,
                                            int kt, int q_g, bool dm, int l15, int quad) {
    #pragma unroll
    for (int nt = 0; nt < 4; nt++) {
        int key0 = kt * 64 + nt * 16 + quad * 4;
        #pragma unroll
        for (int r = 0; r < 4; r++) {
            float pv = __builtin_amdgcn_exp2f(s[nt][r]);
            if (dm && key0 + r > q_g) pv = 0.f;
            s[nt][r] = pv;
        }
    }
    #pragma unroll
    for (int nt = 0; nt < 4; nt++)
        lsum += (s[nt][0] + s[nt][1]) + (s[nt][2] + s[nt][3]);
    #pragma unroll
    for (int nt = 0; nt < 4; nt++) {
        uint2 pk;
        pk.x = cvtpk(s[nt][0], s[nt][1]);
        pk.y = cvtpk(s[nt][2], s[nt][3]);
        int addr = swz(l15, nt * 2 + (quad >> 1)) + (quad & 1) * 4;  // u16 units
        *reinterpret_cast<uint2*>(&pbw[addr]) = pk;
    }
    // same-wave LDS RAW: compiler inserts lgkmcnt wait
    __builtin_amdgcn_s_setprio(1);
    #pragma unroll
    for (int k2 = 0; k2 < 2; k2++) {
        short8 bp = *reinterpret_cast<const short8*>(&pbw[swz(l15, k2 * 4 + quad)]);
        #pragma unroll
        for (int nt = 0; nt < 4; nt++) {
            short8 av = *reinterpret_cast<const short8*>(&vtsc[swz(nt * 16 + l15, k2 * 4 + quad)]);
            o[nt] = __builtin_amdgcn_mfma_f32_16x16x32_bf16(av, bp, o[nt], 0, 0, 0);
        }
    }
    __builtin_amdgcn_s_setprio(0);
}

// ---------------- causal flash attention, qt-PAIRED, K-FROM-REGISTERS.
// Block (b,p,ks) handles qt=63-p AND qt=p (constant 65 tiles, balanced).
// K is NOT staged in LDS: the QK^T A-fragment is wave-uniform, so each wave loads
// kf[8] straight from global (L1 serves waves 1-3). This cuts per-dual-step LDS ops
// 44 -> 26 b128-class (attn is per-CU LDS-BW-bound: R8/R10 showed co-residency
// HURTS, the signature of a shared-LDS bottleneck). kf for tile j+1 is prefetched
// right after the last QK^T consuming tile j. V keeps the single-barrier dbuf.
// Slot-based split-K, nsplit=4 (no atomics/fences; kernel boundary = fence).
__global__ __launch_bounds__(256) void attn(const u16* __restrict__ qp, const u16* __restrict__ kp,
                                            const u16* __restrict__ vp, float* __restrict__ acco,
                                            float* __restrict__ accl, void* __restrict__ outv,
                                            const int* __restrict__ flag, int nsplit) {
    __shared__ __align__(16) u16 vts[2][64 * 64];   // (h, key), swizzled, dbuf (16KB)
    __shared__ __align__(16) u16 pba[4][16 * 64];   // per-wave P^T for qtA (8KB)
    __shared__ __align__(16) u16 pbb[4][16 * 64];   // per-wave P^T for qtB (8KB)
    const int isbf = *flag;
    const int tid = threadIdx.x;
    const int lane = tid & 63;
    const int w = tid >> 6;           // 0..3
    const int l15 = lane & 15;
    const int quad = lane >> 4;

    int u = blockIdx.x;
    int per = 32 * nsplit;
    int b = u / per;
    int rem = u - b * per;
    int p = rem / nsplit;             // pair index 0..31
    int ks = rem - p * nsplit;
    const int qtA = 63 - p;           // large q-tile (>=32)
    const int qtB = p;                // small q-tile (<=31)

    const int q_gA = qtA * 64 + w * 16 + l15;
    const int q_gB = qtB * 64 + w * 16 + l15;

    short8 aqA[2], aqB[2];
    {
        const u16* qr = qp + (size_t)(b * TT + q_gA) * HH;
        aqA[0] = *reinterpret_cast<const short8*>(qr + quad * 8);
        aqA[1] = *reinterpret_cast<const short8*>(qr + 32 + quad * 8);
    }
    {
        const u16* qr = qp + (size_t)(b * TT + q_gB) * HH;
        aqB[0] = *reinterpret_cast<const short8*>(qr + quad * 8);
        aqB[1] = *reinterpret_cast<const short8*>(qr + 32 + quad * 8);
    }

    // staging addresses (tile-invariant)
    const int cc0 = tid, cc1 = tid + 256;
    const int dst0 = swz(cc0 >> 3, cc0 & 7);
    const int dst1 = swz(cc1 >> 3, cc1 & 7);
    const u16* vbase = vp + (size_t)b * 64 * 64 * 64;   // + kt*4096 + cc*8
    const u16* kfb = kp + (size_t)b * TT * HH + l15 * 64 + quad * 8;  // + kt*4096 + nt*1024 + k2*32

    f32x4 zero = {0.f, 0.f, 0.f, 0.f};
    f32x4 oA[4], oB[4];
    #pragma unroll
    for (int i = 0; i < 4; i++) { oA[i] = zero; oB[i] = zero; }
    float lsumA = 0.f, lsumB = 0.f;

    const int nstep = (qtA - ks) / nsplit + 1;   // >= 8 (qtA>=32, ks<=3)

    // prologue: kf for tile t0; stage V t0 into buf0; prefetch V t1 into regs
    short8 kf[8];
    load_kf(kf, kfb, (size_t)ks * 4096);
    uint4 rv0, rv1;
    {
        size_t t0 = (size_t)ks * 4096;
        rv0 = *reinterpret_cast<const uint4*>(vbase + t0 + cc0 * 8);
        rv1 = *reinterpret_cast<const uint4*>(vbase + t0 + cc1 * 8);
    }
    *reinterpret_cast<uint4*>(&vts[0][dst0]) = rv0;
    *reinterpret_cast<uint4*>(&vts[0][dst1]) = rv1;
    if (nstep > 1) {
        size_t t1 = (size_t)(ks + nsplit) * 4096;
        rv0 = *reinterpret_cast<const uint4*>(vbase + t1 + cc0 * 8);
        rv1 = *reinterpret_cast<const uint4*>(vbase + t1 + cc1 * 8);
    }

    for (int j = 0; j < nstep; ++j) {
        __syncthreads();              // separates vts[cur] writes(j-1)/reads(j) AND vts[cur^1] reads(j-1)/writes(j)
        const int cur = j & 1;
        if (j + 1 < nstep) {          // write NEXT tile's V buffer from regs
            *reinterpret_cast<uint4*>(&vts[cur ^ 1][dst0]) = rv0;
            *reinterpret_cast<uint4*>(&vts[cur ^ 1][dst1]) = rv1;
        }
        if (j + 2 < nstep) {          // issue V loads for tile t_{j+2}; fly under compute
            size_t tn = (size_t)(ks + (j + 2) * nsplit) * 4096;
            rv0 = *reinterpret_cast<const uint4*>(vbase + tn + cc0 * 8);
            rv1 = *reinterpret_cast<const uint4*>(vbase + tn + cc1 * 8);
        }
        const int kt = ks + j * nsplit;
        const bool doB = (kt <= qtB);
        const size_t tnext = (size_t)(kt + nsplit) * 4096;

        // A q-tile
        f32x4 sA[4];
        #pragma unroll
        for (int i = 0; i < 4; i++) sA[i] = zero;
        qkt_regs(kf, aqA, sA);
        if (!doB && j + 1 < nstep) load_kf(kf, kfb, tnext);   // kf free after A's QK^T
        smpv(sA, &vts[cur][0], &pba[w][0], oA, lsumA, kt, q_gA, kt == qtA, l15, quad);

        if (doB) {
            f32x4 sB[4];
            #pragma unroll
            for (int i = 0; i < 4; i++) sB[i] = zero;
            qkt_regs(kf, aqB, sB);
            if (j + 1 < nstep) load_kf(kf, kfb, tnext);       // kf free after B's QK^T
            smpv(sB, &vts[cur][0], &pbb[w][0], oB, lsumB, kt, q_gB, kt == qtB, l15, quad);
        }
    }

    // denom: sum the 4 quads' partials (q fixed per thread at l15)
    lsumA += __shfl_xor(lsumA, 16);
    lsumA += __shfl_xor(lsumA, 32);
    lsumB += __shfl_xor(lsumB, 16);
    lsumB += __shfl_xor(lsumB, 32);

    const size_t g0qA = (size_t)(b * TT) + q_gA;
    const size_t g0qB = (size_t)(b * TT) + q_gB;

    if (nsplit == 1) {
        float invA = 1.0f / lsumA;
        float invB = 1.0f / lsumB;
        if (isbf) {
            u16* outp = (u16*)outv;
            #pragma unroll
            for (int nt = 0; nt < 4; nt++) {
                ushort4 sa, sb;
                sa.x = f2bf(oA[nt][0] * invA); sa.y = f2bf(oA[nt][1] * invA);
                sa.z = f2bf(oA[nt][2] * invA); sa.w = f2bf(oA[nt][3] * invA);
                sb.x = f2bf(oB[nt][0] * invB); sb.y = f2bf(oB[nt][1] * invB);
                sb.z = f2bf(oB[nt][2] * invB); sb.w = f2bf(oB[nt][3] * invB);
                *reinterpret_cast<ushort4*>(outp + g0qA * HH + nt * 16 + quad * 4) = sa;
                *reinterpret_cast<ushort4*>(outp + g0qB * HH + nt * 16 + quad * 4) = sb;
            }
        } else {
            float* outp = (float*)outv;
            #pragma unroll
            for (int nt = 0; nt < 4; nt++) {
                float4 sa = {oA[nt][0] * invA, oA[nt][1] * invA, oA[nt][2] * invA, oA[nt][3] * invA};
                float4 sb = {oB[nt][0] * invB, oB[nt][1] * invB, oB[nt][2] * invB, oB[nt][3] * invB};
                *reinterpret_cast<float4*>(outp + g0qA * HH + nt * 16 + quad * 4) = sa;
                *reinterpret_cast<float4*>(outp + g0qB * HH + nt * 16 + quad * 4) = sb;
            }
        }
    } else {
        // slot-based partial writes: (b,qt,ks) owns distinct rows of slot ks
        float* accos = acco + (size_t)ks * (BB * TT * HH);
        float* accls = accl + (size_t)ks * (BB * TT);
        #pragma unroll
        for (int nt = 0; nt < 4; nt++) {
            float4 sv = {oA[nt][0], oA[nt][1], oA[nt][2], oA[nt][3]};
            *reinterpret_cast<float4*>(accos + g0qA * HH + nt * 16 + quad * 4) = sv;
        }
        if (quad == 0) accls[g0qA] = lsumA;
        if (ks <= qtB) {
            #pragma unroll
            for (int nt = 0; nt < 4; nt++) {
                float4 sv = {oB[nt][0], oB[nt][1], oB[nt][2], oB[nt][3]};
                *reinterpret_cast<float4*>(accos + g0qB * HH + nt * 16 + quad * 4) = sv;
            }
            if (quad == 0) accls[g0qB] = lsumB;
        }
    }
}

// ---------------- finalize: out = (sum over active slots of acco) / (sum accl)
__global__ __launch_bounds__(256) void attn_finalize(const float* __restrict__ acco,
                                                     const float* __restrict__ accl,
                                                     void* __restrict__ outv,
                                                     const int* __restrict__ flag, int nsplit) {
    const int isbf = *flag;
    int i = blockIdx.x * blockDim.x + threadIdx.x;   // float4 index over B*T*H
    int row = i >> 4;
    int qt = (row & (TT - 1)) >> 6;
    int nact = min(nsplit, qt + 1);
    float4 ov = reinterpret_cast<const float4*>(acco)[i];
    float l = accl[row];
    for (int s = 1; s < nact; s++) {
        float4 t = reinterpret_cast<const float4*>(acco + (size_t)s * (BB * TT * HH))[i];
        ov.x += t.x; ov.y += t.y; ov.z += t.z; ov.w += t.w;
        l += accl[(size_t)s * (BB * TT) + row];
    }
    float inv = 1.0f / l;
    if (isbf) {
        ushort4 s;
        s.x = f2bf(ov.x * inv); s.y = f2bf(ov.y * inv);
        s.z = f2bf(ov.z * inv); s.w = f2bf(ov.w * inv);
        reinterpret_cast<ushort4*>(outv)[i] = s;
    } else {
        float4 s = {ov.x * inv, ov.y * inv, ov.z * inv, ov.w * inv};
        reinterpret_cast<float4*>(outv)[i] = s;
    }
}

extern "C" void kernel_launch(void* const* d_in, const int* in_sizes, int n_in,
                              void* d_out, int out_size, void* d_ws, size_t ws_size,
                              hipStream_t stream) {
    const void* x  = d_in[0];
    const void* Wk = d_in[1];
    const void* Wq = d_in[2];
    const void* Wv = d_in[3];
    char* ws = (char*)d_ws;
    // ws: qo 0-2M | ko 2-4M | vo 4-6M | Wtp @6M(384K) | flag @6.75M
    //     acco @7M (4 slots x 4M) | accl @39M (4 slots x 64K)
    u16* qo = (u16*)(ws);
    u16* ko = (u16*)(ws + (size_t)2 * 1024 * 1024);
    u16* vo = (u16*)(ws + (size_t)4 * 1024 * 1024);
    u16* Wtp = (u16*)(ws + (size_t)6 * 1024 * 1024);
    int* flag = (int*)(ws + (size_t)6 * 1024 * 1024 + 768 * 1024);
    float* acco = (float*)(ws + (size_t)7 * 1024 * 1024);
    float* accl = (float*)(ws + (size_t)39 * 1024 * 1024);

    const size_t need_split = (size_t)40 * 1024 * 1024;
    const int nsplit = (ws_size >= need_split) ? 4 : 1;

    prep<<<192, 256, 0, stream>>>(Wk, Wq, Wv, (const u16*)x, Wtp, flag);
    qkv_proj<<<512, 256, 0, stream>>>(x, Wtp, qo, ko, vo, flag);
    attn<<<BB * 32 * nsplit, 256, 0, stream>>>(qo, ko, vo, acco, accl, d_out, flag, nsplit);
    if (nsplit > 1) {
        attn_finalize<<<(BB * TT * HH / 4) / 256, 256, 0, stream>>>(acco, accl, d_out, flag, nsplit);
    }
}

// Round 12
// 142.686 us; speedup vs baseline: 1.0867x; 1.0867x over previous
//
#include <hip/hip_runtime.h>

typedef __attribute__((ext_vector_type(8))) short short8;
typedef __attribute__((ext_vector_type(4))) float f32x4;
typedef unsigned short u16;

#define BB 4
#define TT 4096
#define CC 1024
#define HH 64

static __device__ __forceinline__ u16 f2bf(float f) {
    unsigned int u = __float_as_uint(f);
    unsigned int r = (u + 0x7FFFu + ((u >> 16) & 1u)) >> 16;  // RNE
    return (u16)r;
}

// pack 2 f32 -> 2 bf16 in one u32 (lo = first arg); no builtin on gfx950 (T12)
static __device__ __forceinline__ unsigned int cvtpk(float lo, float hi) {
    unsigned int r;
    asm("v_cvt_pk_bf16_f32 %0, %1, %2" : "=v"(r) : "v"(lo), "v"(hi));
    return r;
}

// attn LDS tile addressing: 64-u16 rows, 8 chunks of 8 u16; chunk XOR-swizzled by row&7.
static __device__ __forceinline__ int swz(int row, int chunk) {
    return row * 64 + ((chunk ^ (row & 7)) << 3);
}

static __device__ __forceinline__ int probe_isbf(const u16* xu, int tid) {
    int lane = tid & 63;
    int cnt = 0;
    for (int i = lane; i < 1024; i += 64) {
        u16 u = xu[2 * i];
        int e = (u >> 7) & 0xFF;
        cnt += (e >= 100 && e <= 140) ? 1 : 0;
    }
    for (int d = 1; d < 64; d <<= 1) cnt += __shfl_xor(cnt, d);
    return (cnt > 512) ? 1 : 0;
}

// ---------------- prep: dtype probe + W -> Wtp packed B-fragment order.
// 192 blocks; block 0 additionally publishes the dtype flag.
__global__ void prep(const void* __restrict__ Wk, const void* __restrict__ Wq,
                     const void* __restrict__ Wv, const u16* __restrict__ xu,
                     u16* __restrict__ Wtp, int* __restrict__ flag) {
    __shared__ int sflag;
    if (threadIdx.x < 64) {
        int f = probe_isbf(xu, threadIdx.x);
        if (threadIdx.x == 0) sflag = f;
    }
    __syncthreads();
    const int isbf = sflag;
    if (blockIdx.x == 0 && threadIdx.x == 0) *flag = isbf;

    int r = blockIdx.x;          // global output col 0..191
    int p = r >> 6;              // 0=q 1=k 2=v
    int n = r & 63;
    int nt = n >> 4, nl = n & 15;
    const void* W = (p == 0) ? Wq : (p == 1) ? Wk : Wv;
    int k0 = threadIdx.x * 4;    // 4 consecutive k per thread
    int kb = k0 >> 6, k2 = (k0 >> 5) & 1, quad = (k0 >> 3) & 3, half = (k0 >> 2) & 1;
    ushort4 v;
    if (isbf) {
        const u16* Wb = (const u16*)W;
        v.x = Wb[(k0 + 0) * HH + n]; v.y = Wb[(k0 + 1) * HH + n];
        v.z = Wb[(k0 + 2) * HH + n]; v.w = Wb[(k0 + 3) * HH + n];
    } else {
        const float* Wf = (const float*)W;
        v.x = f2bf(Wf[(k0 + 0) * HH + n]); v.y = f2bf(Wf[(k0 + 1) * HH + n]);
        v.z = f2bf(Wf[(k0 + 2) * HH + n]); v.w = f2bf(Wf[(k0 + 3) * HH + n]);
    }
    size_t off16 = ((size_t)((p * 4 + nt) * 16 + kb) * 2 + k2) * 64 + quad * 16 + nl;
    *reinterpret_cast<ushort4*>(Wtp + off16 * 8 + half * 4) = v;
}

// ---------------- QKV projection v5 (R6 form): 32 rows/block, fused LDS transpose,
// one barrier; compiler handles Wtp load pipelining.
__global__ __launch_bounds__(256) void qkv_proj(const void* __restrict__ x,
                                                const u16* __restrict__ Wtp,
                                                u16* __restrict__ qo, u16* __restrict__ ko,
                                                u16* __restrict__ vo, const int* __restrict__ flag) {
    __shared__ __align__(16) u16 xs[32 * 1024];   // [row][k], 16B chunks swizzled by row&7
    __shared__ __align__(16) u16 tls[4][3][256];  // per-wave, per-proj 16x16 transpose tile
    const int isbf = *flag;
    const int tid = threadIdx.x;
    const int lane = tid & 63;
    const int w = tid >> 6;
    const int l15 = lane & 15;
    const int quad = lane >> 4;
    int phys = blockIdx.x;
    int rb = (phys & 7) * 64 + (phys >> 3);       // XCD-affine 32-row group, 0..511
    const int g0r = rb * 32;

    // ---- stage 32 rows of x (contiguous reads; swizzled 16B-chunk writes)
    #pragma unroll
    for (int j = 0; j < 16; j++) {
        int c = tid + j * 256;                    // 4096 chunks: row = c>>7, ck = c&127
        int row = c >> 7, ck = c & 127;
        int dst = row * 1024 + ((ck ^ (row & 7)) << 3);
        if (isbf) {
            uint4 d = *reinterpret_cast<const uint4*>((const u16*)x + (size_t)(g0r + row) * CC + ck * 8);
            *reinterpret_cast<uint4*>(xs + dst) = d;
        } else {
            const float4* pf = reinterpret_cast<const float4*>((const float*)x + (size_t)(g0r + row) * CC + ck * 8);
            float4 a0 = pf[0], a1 = pf[1];
            ushort4 lo; lo.x = f2bf(a0.x); lo.y = f2bf(a0.y); lo.z = f2bf(a0.z); lo.w = f2bf(a0.w);
            ushort4 hi; hi.x = f2bf(a1.x); hi.y = f2bf(a1.y); hi.z = f2bf(a1.z); hi.w = f2bf(a1.w);
            *reinterpret_cast<ushort4*>(xs + dst) = lo;
            *reinterpret_cast<ushort4*>(xs + dst + 4) = hi;
        }
    }
    __syncthreads();                              // the ONLY block-wide barrier

    f32x4 zero = {0.f, 0.f, 0.f, 0.f};
    f32x4 acc[3][2];                              // [proj][row-tile]
    #pragma unroll
    for (int i = 0; i < 3; i++) { acc[i][0] = zero; acc[i][1] = zero; }

    for (int kb = 0; kb < 16; kb++) {
        #pragma unroll
        for (int k2 = 0; k2 < 2; k2++) {
            int ck = kb * 8 + k2 * 4 + quad;
            int xo = ((ck ^ (l15 & 7)) << 3);
            short8 af0 = *reinterpret_cast<const short8*>(xs + l15 * 1024 + xo);
            short8 af1 = *reinterpret_cast<const short8*>(xs + (16 + l15) * 1024 + xo);
            #pragma unroll
            for (int p = 0; p < 3; p++) {
                short8 bf = *reinterpret_cast<const short8*>(
                    Wtp + ((((size_t)(p * 4 + w) * 16 + kb) * 2 + k2) * 64 + lane) * 8);
                acc[p][0] = __builtin_amdgcn_mfma_f32_16x16x32_bf16(af0, bf, acc[p][0], 0, 0, 0);
                acc[p][1] = __builtin_amdgcn_mfma_f32_16x16x32_bf16(af1, bf, acc[p][1], 0, 0, 0);
            }
        }
    }

    // ---- epilogue per row-tile: per-wave 16x16 LDS transpose, 8B coalesced stores
    const float qscale = 0.18033688011112042f;    // log2(e)/8
    #pragma unroll
    for (int rt = 0; rt < 2; rt++) {
        const int g0rt = g0r + rt * 16;
        #pragma unroll
        for (int p = 0; p < 3; p++) {
            if (p < 2) {
                float sc = (p == 0) ? qscale : 1.f;
                #pragma unroll
                for (int r = 0; r < 4; r++)       // [t(16)][c(16)]
                    tls[w][p][(quad * 4 + r) * 16 + l15] = f2bf(acc[p][rt][r] * sc);
            } else {
                #pragma unroll
                for (int r = 0; r < 4; r++)       // [c(16)][t(16)]
                    tls[w][p][l15 * 16 + quad * 4 + r] = f2bf(acc[p][rt][r]);
            }
        }
        // same-wave LDS RAW: compiler inserts lgkmcnt wait; no barrier needed
        #pragma unroll
        for (int p = 0; p < 2; p++) {             // q, k: row-major (g0rt+t)*64 + w*16+c
            int t = lane >> 2, seg = lane & 3;
            ushort4 d = *reinterpret_cast<const ushort4*>(&tls[w][p][t * 16 + seg * 4]);
            u16* dst = (p == 0) ? qo : ko;
            *reinterpret_cast<ushort4*>(dst + (size_t)(g0rt + t) * HH + w * 16 + seg * 4) = d;
        }
        {                                         // v: vo[b][kt][h][64keys]
            int c = lane >> 2, seg = lane & 3;
            ushort4 d = *reinterpret_cast<const ushort4*>(&tls[w][2][c * 16 + seg * 4]);
            int b = g0rt >> 12;
            int kt = (g0rt & 4095) >> 6;
            int toff = g0rt & 63;
            *reinterpret_cast<ushort4*>(vo + ((size_t)((b * 64 + kt) * 64 + w * 16 + c)) * 64 + toff + seg * 4) = d;
        }
    }
}

// QK^T: S^T = mfma(K_frag from LDS, Q_frag)
static __device__ __forceinline__ void qkt(const u16* __restrict__ kstc, const short8* aq,
                                           f32x4* s, int l15, int quad) {
    __builtin_amdgcn_s_setprio(1);
    #pragma unroll
    for (int k2 = 0; k2 < 2; k2++) {
        #pragma unroll
        for (int nt = 0; nt < 4; nt++) {
            short8 af = *reinterpret_cast<const short8*>(&kstc[swz(nt * 16 + l15, k2 * 4 + quad)]);
            s[nt] = __builtin_amdgcn_mfma_f32_16x16x32_bf16(af, aq[k2], s[nt], 0, 0, 0);
        }
    }
    __builtin_amdgcn_s_setprio(0);
}

// softmax on S^T: exp2, causal mask, lsum accumulate, pack+store P^T into pb
static __device__ __forceinline__ void sm_store(f32x4* s, u16* __restrict__ pbw, float& lsum,
                                                int kt, int q_g, bool dm, int l15, int quad) {
    #pragma unroll
    for (int nt = 0; nt < 4; nt++) {
        int key0 = kt * 64 + nt * 16 + quad * 4;
        #pragma unroll
        for (int r = 0; r < 4; r++) {
            float pv = __builtin_amdgcn_exp2f(s[nt][r]);
            if (dm && key0 + r > q_g) pv = 0.f;
            s[nt][r] = pv;
        }
    }
    #pragma unroll
    for (int nt = 0; nt < 4; nt++)
        lsum += (s[nt][0] + s[nt][1]) + (s[nt][2] + s[nt][3]);
    #pragma unroll
    for (int nt = 0; nt < 4; nt++) {
        uint2 pk;
        pk.x = cvtpk(s[nt][0], s[nt][1]);
        pk.y = cvtpk(s[nt][2], s[nt][3]);
        int addr = swz(l15, nt * 2 + (quad >> 1)) + (quad & 1) * 4;  // u16 units
        *reinterpret_cast<uint2*>(&pbw[addr]) = pk;
    }
}

// PV: O^T += mfma(V_frag from LDS, P_frag from pb)  (same-wave RAW on pb)
static __device__ __forceinline__ void pv(const u16* __restrict__ vtsc,
                                          const u16* __restrict__ pbw,
                                          f32x4* o, int l15, int quad) {
    __builtin_amdgcn_s_setprio(1);
    #pragma unroll
    for (int k2 = 0; k2 < 2; k2++) {
        short8 bp = *reinterpret_cast<const short8*>(&pbw[swz(l15, k2 * 4 + quad)]);
        #pragma unroll
        for (int nt = 0; nt < 4; nt++) {
            short8 av = *reinterpret_cast<const short8*>(&vtsc[swz(nt * 16 + l15, k2 * 4 + quad)]);
            o[nt] = __builtin_amdgcn_mfma_f32_16x16x32_bf16(av, bp, o[nt], 0, 0, 0);
        }
    }
    __builtin_amdgcn_s_setprio(0);
}

// ---------------- causal flash attention, qt-PAIRED with STAGGERED dual steps.
// Block (b,p,ks) handles qt=63-p AND qt=p (constant 65 tiles, balanced, 512 blocks).
// R11 counters: MfmaUtil 7%, VALUBusy 22%, occupancy 15% -> attn is dependency-
// LATENCY bound; the dominant exposed stall is the pb ds_write -> ds_read RAW
// (~150cy, twice per dual step). Stagger: QK_A, sm_A(->pbA), QK_B, sm_B(->pbB),
// PV_A, PV_B — pbA's RAW hides under QK_B+sm_B, pbB's under PV_A. Pure reorder
// of R6's ops (no extra LDS; sB live only briefly).
// Single-barrier double-buffered K/V staging; slot-based split-K, nsplit=4.
__global__ __launch_bounds__(256) void attn(const u16* __restrict__ qp, const u16* __restrict__ kp,
                                            const u16* __restrict__ vp, float* __restrict__ acco,
                                            float* __restrict__ accl, void* __restrict__ outv,
                                            const int* __restrict__ flag, int nsplit) {
    __shared__ __align__(16) u16 kst[2][64 * 64];   // (key, h), swizzled, dbuf
    __shared__ __align__(16) u16 vts[2][64 * 64];   // (h, key), swizzled, dbuf
    __shared__ __align__(16) u16 pba[4][16 * 64];   // per-wave P^T for qtA
    __shared__ __align__(16) u16 pbb[4][16 * 64];   // per-wave P^T for qtB
    const int isbf = *flag;
    const int tid = threadIdx.x;
    const int lane = tid & 63;
    const int w = tid >> 6;           // 0..3
    const int l15 = lane & 15;
    const int quad = lane >> 4;

    int u = blockIdx.x;
    int per = 32 * nsplit;
    int b = u / per;
    int rem = u - b * per;
    int p = rem / nsplit;             // pair index 0..31
    int ks = rem - p * nsplit;
    const int qtA = 63 - p;           // large q-tile (>=32)
    const int qtB = p;                // small q-tile (<=31)

    const int q_gA = qtA * 64 + w * 16 + l15;
    const int q_gB = qtB * 64 + w * 16 + l15;

    short8 aqA[2], aqB[2];
    {
        const u16* qr = qp + (size_t)(b * TT + q_gA) * HH;
        aqA[0] = *reinterpret_cast<const short8*>(qr + quad * 8);
        aqA[1] = *reinterpret_cast<const short8*>(qr + 32 + quad * 8);
    }
    {
        const u16* qr = qp + (size_t)(b * TT + q_gB) * HH;
        aqB[0] = *reinterpret_cast<const short8*>(qr + quad * 8);
        aqB[1] = *reinterpret_cast<const short8*>(qr + 32 + quad * 8);
    }

    // staging addresses (tile-invariant)
    const int cc0 = tid, cc1 = tid + 256;
    const int dst0 = swz(cc0 >> 3, cc0 & 7);
    const int dst1 = swz(cc1 >> 3, cc1 & 7);
    const u16* kbase = kp + (size_t)b * TT * HH;        // + kt*4096 + cc*8
    const u16* vbase = vp + (size_t)b * 64 * 64 * 64;   // + kt*4096 + cc*8

    f32x4 zero = {0.f, 0.f, 0.f, 0.f};
    f32x4 oA[4], oB[4];
    #pragma unroll
    for (int i = 0; i < 4; i++) { oA[i] = zero; oB[i] = zero; }
    float lsumA = 0.f, lsumB = 0.f;

    const int nstep = (qtA - ks) / nsplit + 1;   // >= 8 (qtA>=32, ks<=3)

    // prologue: stage tile t0 into buf0; prefetch t1 into regs
    uint4 rk0, rk1, rv0, rv1;
    {
        size_t t0 = (size_t)ks * 4096;
        rk0 = *reinterpret_cast<const uint4*>(kbase + t0 + cc0 * 8);
        rk1 = *reinterpret_cast<const uint4*>(kbase + t0 + cc1 * 8);
        rv0 = *reinterpret_cast<const uint4*>(vbase + t0 + cc0 * 8);
        rv1 = *reinterpret_cast<const uint4*>(vbase + t0 + cc1 * 8);
    }
    *reinterpret_cast<uint4*>(&kst[0][dst0]) = rk0;
    *reinterpret_cast<uint4*>(&kst[0][dst1]) = rk1;
    *reinterpret_cast<uint4*>(&vts[0][dst0]) = rv0;
    *reinterpret_cast<uint4*>(&vts[0][dst1]) = rv1;
    if (nstep > 1) {
        size_t t1 = (size_t)(ks + nsplit) * 4096;
        rk0 = *reinterpret_cast<const uint4*>(kbase + t1 + cc0 * 8);
        rk1 = *reinterpret_cast<const uint4*>(kbase + t1 + cc1 * 8);
        rv0 = *reinterpret_cast<const uint4*>(vbase + t1 + cc0 * 8);
        rv1 = *reinterpret_cast<const uint4*>(vbase + t1 + cc1 * 8);
    }

    for (int j = 0; j < nstep; ++j) {
        __syncthreads();              // separates buf[cur] writes(j-1)/reads(j) AND buf[cur^1] reads(j-1)/writes(j)
        const int cur = j & 1;
        if (j + 1 < nstep) {          // write NEXT tile's buffer from regs
            *reinterpret_cast<uint4*>(&kst[cur ^ 1][dst0]) = rk0;
            *reinterpret_cast<uint4*>(&kst[cur ^ 1][dst1]) = rk1;
            *reinterpret_cast<uint4*>(&vts[cur ^ 1][dst0]) = rv0;
            *reinterpret_cast<uint4*>(&vts[cur ^ 1][dst1]) = rv1;
        }
        if (j + 2 < nstep) {          // issue loads for tile t_{j+2}; fly under compute
            size_t tn = (size_t)(ks + (j + 2) * nsplit) * 4096;
            rk0 = *reinterpret_cast<const uint4*>(kbase + tn + cc0 * 8);
            rk1 = *reinterpret_cast<const uint4*>(kbase + tn + cc1 * 8);
            rv0 = *reinterpret_cast<const uint4*>(vbase + tn + cc0 * 8);
            rv1 = *reinterpret_cast<const uint4*>(vbase + tn + cc1 * 8);
        }
        const int kt = ks + j * nsplit;
        const bool doB = (kt <= qtB);

        f32x4 sA[4];
        #pragma unroll
        for (int i = 0; i < 4; i++) sA[i] = zero;
        qkt(&kst[cur][0], aqA, sA, l15, quad);
        sm_store(sA, &pba[w][0], lsumA, kt, q_gA, kt == qtA, l15, quad);
        if (doB) {
            f32x4 sB[4];
            #pragma unroll
            for (int i = 0; i < 4; i++) sB[i] = zero;
            qkt(&kst[cur][0], aqB, sB, l15, quad);       // covers pbA's write->read RAW
            sm_store(sB, &pbb[w][0], lsumB, kt, q_gB, kt == qtB, l15, quad);
            pv(&vts[cur][0], &pba[w][0], oA, l15, quad); // covers pbB's RAW
            pv(&vts[cur][0], &pbb[w][0], oB, l15, quad);
        } else {
            pv(&vts[cur][0], &pba[w][0], oA, l15, quad);
        }
    }

    // denom: sum the 4 quads' partials (q fixed per thread at l15)
    lsumA += __shfl_xor(lsumA, 16);
    lsumA += __shfl_xor(lsumA, 32);
    lsumB += __shfl_xor(lsumB, 16);
    lsumB += __shfl_xor(lsumB, 32);

    const size_t g0qA = (size_t)(b * TT) + q_gA;
    const size_t g0qB = (size_t)(b * TT) + q_gB;

    if (nsplit == 1) {
        float invA = 1.0f / lsumA;
        float invB = 1.0f / lsumB;
        if (isbf) {
            u16* outp = (u16*)outv;
            #pragma unroll
            for (int nt = 0; nt < 4; nt++) {
                ushort4 sa, sb;
                sa.x = f2bf(oA[nt][0] * invA); sa.y = f2bf(oA[nt][1] * invA);
                sa.z = f2bf(oA[nt][2] * invA); sa.w = f2bf(oA[nt][3] * invA);
                sb.x = f2bf(oB[nt][0] * invB); sb.y = f2bf(oB[nt][1] * invB);
                sb.z = f2bf(oB[nt][2] * invB); sb.w = f2bf(oB[nt][3] * invB);
                *reinterpret_cast<ushort4*>(outp + g0qA * HH + nt * 16 + quad * 4) = sa;
                *reinterpret_cast<ushort4*>(outp + g0qB * HH + nt * 16 + quad * 4) = sb;
            }
        } else {
            float* outp = (float*)outv;
            #pragma unroll
            for (int nt = 0; nt < 4; nt++) {
                float4 sa = {oA[nt][0] * invA, oA[nt][1] * invA, oA[nt][2] * invA, oA[nt][3] * invA};
                float4 sb = {oB[nt][0] * invB, oB[nt][1] * invB, oB[nt][2] * invB, oB[nt][3] * invB};
                *reinterpret_cast<float4*>(outp + g0qA * HH + nt * 16 + quad * 4) = sa;
                *reinterpret_cast<float4*>(outp + g0qB * HH + nt * 16 + quad * 4) = sb;
            }
        }
    } else {
        // slot-based partial writes: (b,qt,ks) owns distinct rows of slot ks
        float* accos = acco + (size_t)ks * (BB * TT * HH);
        float* accls = accl + (size_t)ks * (BB * TT);
        #pragma unroll
        for (int nt = 0; nt < 4; nt++) {
            float4 sv = {oA[nt][0], oA[nt][1], oA[nt][2], oA[nt][3]};
            *reinterpret_cast<float4*>(accos + g0qA * HH + nt * 16 + quad * 4) = sv;
        }
        if (quad == 0) accls[g0qA] = lsumA;
        if (ks <= qtB) {
            #pragma unroll
            for (int nt = 0; nt < 4; nt++) {
                float4 sv = {oB[nt][0], oB[nt][1], oB[nt][2], oB[nt][3]};
                *reinterpret_cast<float4*>(accos + g0qB * HH + nt * 16 + quad * 4) = sv;
            }
            if (quad == 0) accls[g0qB] = lsumB;
        }
    }
}

// ---------------- finalize: out = (sum over active slots of acco) / (sum accl)
__global__ __launch_bounds__(256) void attn_finalize(const float* __restrict__ acco,
                                                     const float* __restrict__ accl,
                                                     void* __restrict__ outv,
                                                     const int* __restrict__ flag, int nsplit) {
    const int isbf = *flag;
    int i = blockIdx.x * blockDim.x + threadIdx.x;   // float4 index over B*T*H
    int row = i >> 4;
    int qt = (row & (TT - 1)) >> 6;
    int nact = min(nsplit, qt + 1);
    float4 ov = reinterpret_cast<const float4*>(acco)[i];
    float l = accl[row];
    for (int s = 1; s < nact; s++) {
        float4 t = reinterpret_cast<const float4*>(acco + (size_t)s * (BB * TT * HH))[i];
        ov.x += t.x; ov.y += t.y; ov.z += t.z; ov.w += t.w;
        l += accl[(size_t)s * (BB * TT) + row];
    }
    float inv = 1.0f / l;
    if (isbf) {
        ushort4 s;
        s.x = f2bf(ov.x * inv); s.y = f2bf(ov.y * inv);
        s.z = f2bf(ov.z * inv); s.w = f2bf(ov.w * inv);
        reinterpret_cast<ushort4*>(outv)[i] = s;
    } else {
        float4 s = {ov.x * inv, ov.y * inv, ov.z * inv, ov.w * inv};
        reinterpret_cast<float4*>(outv)[i] = s;
    }
}

extern "C" void kernel_launch(void* const* d_in, const int* in_sizes, int n_in,
                              void* d_out, int out_size, void* d_ws, size_t ws_size,
                              hipStream_t stream) {
    const void* x  = d_in[0];
    const void* Wk = d_in[1];
    const void* Wq = d_in[2];
    const void* Wv = d_in[3];
    char* ws = (char*)d_ws;
    // ws: qo 0-2M | ko 2-4M | vo 4-6M | Wtp @6M(384K) | flag @6.75M
    //     acco @7M (4 slots x 4M) | accl @39M (4 slots x 64K)
    u16* qo = (u16*)(ws);
    u16* ko = (u16*)(ws + (size_t)2 * 1024 * 1024);
    u16* vo = (u16*)(ws + (size_t)4 * 1024 * 1024);
    u16* Wtp = (u16*)(ws + (size_t)6 * 1024 * 1024);
    int* flag = (int*)(ws + (size_t)6 * 1024 * 1024 + 768 * 1024);
    float* acco = (float*)(ws + (size_t)7 * 1024 * 1024);
    float* accl = (float*)(ws + (size_t)39 * 1024 * 1024);

    const size_t need_split = (size_t)40 * 1024 * 1024;
    const int nsplit = (ws_size >= need_split) ? 4 : 1;

    prep<<<192, 256, 0, stream>>>(Wk, Wq, Wv, (const u16*)x, Wtp, flag);
    qkv_proj<<<512, 256, 0, stream>>>(x, Wtp, qo, ko, vo, flag);
    attn<<<BB * 32 * nsplit, 256, 0, stream>>>(qo, ko, vo, acco, accl, d_out, flag, nsplit);
    if (nsplit > 1) {
        attn_finalize<<<(BB * TT * HH / 4) / 256, 256, 0, stream>>>(acco, accl, d_out, flag, nsplit);
    }
}

// Round 13
// 141.762 us; speedup vs baseline: 1.0938x; 1.0065x over previous
//
#include <hip/hip_runtime.h>

typedef __attribute__((ext_vector_type(8))) short short8;
typedef __attribute__((ext_vector_type(4))) float f32x4;
typedef unsigned short u16;

#define BB 4
#define TT 4096
#define CC 1024
#define HH 64

static __device__ __forceinline__ u16 f2bf(float f) {
    unsigned int u = __float_as_uint(f);
    unsigned int r = (u + 0x7FFFu + ((u >> 16) & 1u)) >> 16;  // RNE
    return (u16)r;
}

// pack 2 f32 -> 2 bf16 in one u32 (lo = first arg); no builtin on gfx950 (T12)
static __device__ __forceinline__ unsigned int cvtpk(float lo, float hi) {
    unsigned int r;
    asm("v_cvt_pk_bf16_f32 %0, %1, %2" : "=v"(r) : "v"(lo), "v"(hi));
    return r;
}

// attn LDS tile addressing: 64-u16 rows, 8 chunks of 8 u16; chunk XOR-swizzled by row&7.
static __device__ __forceinline__ int swz(int row, int chunk) {
    return row * 64 + ((chunk ^ (row & 7)) << 3);
}

static __device__ __forceinline__ int probe_isbf(const u16* xu, int tid) {
    int lane = tid & 63;
    int cnt = 0;
    for (int i = lane; i < 1024; i += 64) {
        u16 u = xu[2 * i];
        int e = (u >> 7) & 0xFF;
        cnt += (e >= 100 && e <= 140) ? 1 : 0;
    }
    for (int d = 1; d < 64; d <<= 1) cnt += __shfl_xor(cnt, d);
    return (cnt > 512) ? 1 : 0;
}

// ---------------- prep: dtype probe + W -> Wtp packed B-fragment order.
// 192 blocks; block 0 additionally publishes the dtype flag.
__global__ void prep(const void* __restrict__ Wk, const void* __restrict__ Wq,
                     const void* __restrict__ Wv, const u16* __restrict__ xu,
                     u16* __restrict__ Wtp, int* __restrict__ flag) {
    __shared__ int sflag;
    if (threadIdx.x < 64) {
        int f = probe_isbf(xu, threadIdx.x);
        if (threadIdx.x == 0) sflag = f;
    }
    __syncthreads();
    const int isbf = sflag;
    if (blockIdx.x == 0 && threadIdx.x == 0) *flag = isbf;

    int r = blockIdx.x;          // global output col 0..191
    int p = r >> 6;              // 0=q 1=k 2=v
    int n = r & 63;
    int nt = n >> 4, nl = n & 15;
    const void* W = (p == 0) ? Wq : (p == 1) ? Wk : Wv;
    int k0 = threadIdx.x * 4;    // 4 consecutive k per thread
    int kb = k0 >> 6, k2 = (k0 >> 5) & 1, quad = (k0 >> 3) & 3, half = (k0 >> 2) & 1;
    ushort4 v;
    if (isbf) {
        const u16* Wb = (const u16*)W;
        v.x = Wb[(k0 + 0) * HH + n]; v.y = Wb[(k0 + 1) * HH + n];
        v.z = Wb[(k0 + 2) * HH + n]; v.w = Wb[(k0 + 3) * HH + n];
    } else {
        const float* Wf = (const float*)W;
        v.x = f2bf(Wf[(k0 + 0) * HH + n]); v.y = f2bf(Wf[(k0 + 1) * HH + n]);
        v.z = f2bf(Wf[(k0 + 2) * HH + n]); v.w = f2bf(Wf[(k0 + 3) * HH + n]);
    }
    size_t off16 = ((size_t)((p * 4 + nt) * 16 + kb) * 2 + k2) * 64 + quad * 16 + nl;
    *reinterpret_cast<ushort4*>(Wtp + off16 * 8 + half * 4) = v;
}

// ---------------- QKV projection v5 (R6 form): 32 rows/block, fused LDS transpose,
// one barrier; compiler handles Wtp load pipelining.
__global__ __launch_bounds__(256) void qkv_proj(const void* __restrict__ x,
                                                const u16* __restrict__ Wtp,
                                                u16* __restrict__ qo, u16* __restrict__ ko,
                                                u16* __restrict__ vo, const int* __restrict__ flag) {
    __shared__ __align__(16) u16 xs[32 * 1024];   // [row][k], 16B chunks swizzled by row&7
    __shared__ __align__(16) u16 tls[4][3][256];  // per-wave, per-proj 16x16 transpose tile
    const int isbf = *flag;
    const int tid = threadIdx.x;
    const int lane = tid & 63;
    const int w = tid >> 6;
    const int l15 = lane & 15;
    const int quad = lane >> 4;
    int phys = blockIdx.x;
    int rb = (phys & 7) * 64 + (phys >> 3);       // XCD-affine 32-row group, 0..511
    const int g0r = rb * 32;

    // ---- stage 32 rows of x (contiguous reads; swizzled 16B-chunk writes)
    #pragma unroll
    for (int j = 0; j < 16; j++) {
        int c = tid + j * 256;                    // 4096 chunks: row = c>>7, ck = c&127
        int row = c >> 7, ck = c & 127;
        int dst = row * 1024 + ((ck ^ (row & 7)) << 3);
        if (isbf) {
            uint4 d = *reinterpret_cast<const uint4*>((const u16*)x + (size_t)(g0r + row) * CC + ck * 8);
            *reinterpret_cast<uint4*>(xs + dst) = d;
        } else {
            const float4* pf = reinterpret_cast<const float4*>((const float*)x + (size_t)(g0r + row) * CC + ck * 8);
            float4 a0 = pf[0], a1 = pf[1];
            ushort4 lo; lo.x = f2bf(a0.x); lo.y = f2bf(a0.y); lo.z = f2bf(a0.z); lo.w = f2bf(a0.w);
            ushort4 hi; hi.x = f2bf(a1.x); hi.y = f2bf(a1.y); hi.z = f2bf(a1.z); hi.w = f2bf(a1.w);
            *reinterpret_cast<ushort4*>(xs + dst) = lo;
            *reinterpret_cast<ushort4*>(xs + dst + 4) = hi;
        }
    }
    __syncthreads();                              // the ONLY block-wide barrier

    f32x4 zero = {0.f, 0.f, 0.f, 0.f};
    f32x4 acc[3][2];                              // [proj][row-tile]
    #pragma unroll
    for (int i = 0; i < 3; i++) { acc[i][0] = zero; acc[i][1] = zero; }

    for (int kb = 0; kb < 16; kb++) {
        #pragma unroll
        for (int k2 = 0; k2 < 2; k2++) {
            int ck = kb * 8 + k2 * 4 + quad;
            int xo = ((ck ^ (l15 & 7)) << 3);
            short8 af0 = *reinterpret_cast<const short8*>(xs + l15 * 1024 + xo);
            short8 af1 = *reinterpret_cast<const short8*>(xs + (16 + l15) * 1024 + xo);
            #pragma unroll
            for (int p = 0; p < 3; p++) {
                short8 bf = *reinterpret_cast<const short8*>(
                    Wtp + ((((size_t)(p * 4 + w) * 16 + kb) * 2 + k2) * 64 + lane) * 8);
                acc[p][0] = __builtin_amdgcn_mfma_f32_16x16x32_bf16(af0, bf, acc[p][0], 0, 0, 0);
                acc[p][1] = __builtin_amdgcn_mfma_f32_16x16x32_bf16(af1, bf, acc[p][1], 0, 0, 0);
            }
        }
    }

    // ---- epilogue per row-tile: per-wave 16x16 LDS transpose, 8B coalesced stores
    const float qscale = 0.18033688011112042f;    // log2(e)/8
    #pragma unroll
    for (int rt = 0; rt < 2; rt++) {
        const int g0rt = g0r + rt * 16;
        #pragma unroll
        for (int p = 0; p < 3; p++) {
            if (p < 2) {
                float sc = (p == 0) ? qscale : 1.f;
                #pragma unroll
                for (int r = 0; r < 4; r++)       // [t(16)][c(16)]
                    tls[w][p][(quad * 4 + r) * 16 + l15] = f2bf(acc[p][rt][r] * sc);
            } else {
                #pragma unroll
                for (int r = 0; r < 4; r++)       // [c(16)][t(16)]
                    tls[w][p][l15 * 16 + quad * 4 + r] = f2bf(acc[p][rt][r]);
            }
        }
        // same-wave LDS RAW: compiler inserts lgkmcnt wait; no barrier needed
        #pragma unroll
        for (int p = 0; p < 2; p++) {             // q, k: row-major (g0rt+t)*64 + w*16+c
            int t = lane >> 2, seg = lane & 3;
            ushort4 d = *reinterpret_cast<const ushort4*>(&tls[w][p][t * 16 + seg * 4]);
            u16* dst = (p == 0) ? qo : ko;
            *reinterpret_cast<ushort4*>(dst + (size_t)(g0rt + t) * HH + w * 16 + seg * 4) = d;
        }
        {                                         // v: vo[b][kt][h][64keys]
            int c = lane >> 2, seg = lane & 3;
            ushort4 d = *reinterpret_cast<const ushort4*>(&tls[w][2][c * 16 + seg * 4]);
            int b = g0rt >> 12;
            int kt = (g0rt & 4095) >> 6;
            int toff = g0rt & 63;
            *reinterpret_cast<ushort4*>(vo + ((size_t)((b * 64 + kt) * 64 + w * 16 + c)) * 64 + toff + seg * 4) = d;
        }
    }
}

// QK^T: S^T = mfma(K_frag from LDS, Q_frag)
static __device__ __forceinline__ void qkt(const u16* __restrict__ kstc, const short8* aq,
                                           f32x4* s, int l15, int quad) {
    __builtin_amdgcn_s_setprio(1);
    #pragma unroll
    for (int k2 = 0; k2 < 2; k2++) {
        #pragma unroll
        for (int nt = 0; nt < 4; nt++) {
            short8 af = *reinterpret_cast<const short8*>(&kstc[swz(nt * 16 + l15, k2 * 4 + quad)]);
            s[nt] = __builtin_amdgcn_mfma_f32_16x16x32_bf16(af, aq[k2], s[nt], 0, 0, 0);
        }
    }
    __builtin_amdgcn_s_setprio(0);
}

// softmax on S^T, P packed IN REGISTERS (no LDS round-trip).
// Key->slot bijection f(k2,quad,j) = (2k2+(j>>2))*16 + quad*4 + (j&3) makes the
// PV B-fragment lane-local: bp[k2] = {pk(s[2k2]01), pk(s[2k2]23), pk(s[2k2+1]01),
// pk(s[2k2+1]23)}. V's A-frag is read at the SAME remapped key slots (pv_reg).
static __device__ __forceinline__ void sm_pack(f32x4* s, short8* bp, float& lsum,
                                               int kt, int q_g, bool dm, int l15, int quad) {
    #pragma unroll
    for (int nt = 0; nt < 4; nt++) {
        int key0 = kt * 64 + nt * 16 + quad * 4;
        #pragma unroll
        for (int r = 0; r < 4; r++) {
            float pv = __builtin_amdgcn_exp2f(s[nt][r]);
            if (dm && key0 + r > q_g) pv = 0.f;
            s[nt][r] = pv;
        }
    }
    #pragma unroll
    for (int nt = 0; nt < 4; nt++)
        lsum += (s[nt][0] + s[nt][1]) + (s[nt][2] + s[nt][3]);
    #pragma unroll
    for (int k2 = 0; k2 < 2; k2++) {
        union { short8 v; unsigned int u[4]; } t;
        t.u[0] = cvtpk(s[2 * k2][0], s[2 * k2][1]);
        t.u[1] = cvtpk(s[2 * k2][2], s[2 * k2][3]);
        t.u[2] = cvtpk(s[2 * k2 + 1][0], s[2 * k2 + 1][1]);
        t.u[3] = cvtpk(s[2 * k2 + 1][2], s[2 * k2 + 1][3]);
        bp[k2] = t.v;
    }
}

// PV with register P: av[j] = V^T[h=nt*16+l15][key=f(k2,quad,j)] via two b64 reads
// (cols 32k2+quad*4 and 32k2+16+quad*4 of the swizzled vts row).
static __device__ __forceinline__ void pv_reg(const u16* __restrict__ vtsc, const short8* bp,
                                              f32x4* o, int l15, int quad) {
    __builtin_amdgcn_s_setprio(1);
    #pragma unroll
    for (int k2 = 0; k2 < 2; k2++) {
        #pragma unroll
        for (int nt = 0; nt < 4; nt++) {
            int row = nt * 16 + l15;
            int base = row * 64;
            int r7 = row & 7;
            int off = (quad & 1) * 4;
            int c0 = 4 * k2 + (quad >> 1);
            union { short8 v; ushort4 h[2]; } av;
            av.h[0] = *reinterpret_cast<const ushort4*>(&vtsc[base + ((c0 ^ r7) << 3) + off]);
            av.h[1] = *reinterpret_cast<const ushort4*>(&vtsc[base + (((c0 + 2) ^ r7) << 3) + off]);
            o[nt] = __builtin_amdgcn_mfma_f32_16x16x32_bf16(av.v, bp[k2], o[nt], 0, 0, 0);
        }
    }
    __builtin_amdgcn_s_setprio(0);
}

// ---------------- causal flash attention, qt-PAIRED, P IN REGISTERS.
// Block (b,p,ks) handles qt=63-p AND qt=p (constant 65 tiles, balanced, 512 blocks).
// R11 counters showed attn is dependency-latency bound; the dominant exposed stall
// was the P LDS write->read RAW. P now never touches LDS: the MFMA key-contraction
// order is remapped so the PV B-frag is lane-local after cvt_pk (T12's "make the
// reduction axis lane-local", with zero cross-lane ops). LDS 48->32KB.
// Single-barrier double-buffered K/V staging; slot-based split-K, nsplit=4.
__global__ __launch_bounds__(256) void attn(const u16* __restrict__ qp, const u16* __restrict__ kp,
                                            const u16* __restrict__ vp, float* __restrict__ acco,
                                            float* __restrict__ accl, void* __restrict__ outv,
                                            const int* __restrict__ flag, int nsplit) {
    __shared__ __align__(16) u16 kst[2][64 * 64];   // (key, h), swizzled, dbuf
    __shared__ __align__(16) u16 vts[2][64 * 64];   // (h, key), swizzled, dbuf
    const int isbf = *flag;
    const int tid = threadIdx.x;
    const int lane = tid & 63;
    const int w = tid >> 6;           // 0..3
    const int l15 = lane & 15;
    const int quad = lane >> 4;

    int u = blockIdx.x;
    int per = 32 * nsplit;
    int b = u / per;
    int rem = u - b * per;
    int p = rem / nsplit;             // pair index 0..31
    int ks = rem - p * nsplit;
    const int qtA = 63 - p;           // large q-tile (>=32)
    const int qtB = p;                // small q-tile (<=31)

    const int q_gA = qtA * 64 + w * 16 + l15;
    const int q_gB = qtB * 64 + w * 16 + l15;

    short8 aqA[2], aqB[2];
    {
        const u16* qr = qp + (size_t)(b * TT + q_gA) * HH;
        aqA[0] = *reinterpret_cast<const short8*>(qr + quad * 8);
        aqA[1] = *reinterpret_cast<const short8*>(qr + 32 + quad * 8);
    }
    {
        const u16* qr = qp + (size_t)(b * TT + q_gB) * HH;
        aqB[0] = *reinterpret_cast<const short8*>(qr + quad * 8);
        aqB[1] = *reinterpret_cast<const short8*>(qr + 32 + quad * 8);
    }

    // staging addresses (tile-invariant)
    const int cc0 = tid, cc1 = tid + 256;
    const int dst0 = swz(cc0 >> 3, cc0 & 7);
    const int dst1 = swz(cc1 >> 3, cc1 & 7);
    const u16* kbase = kp + (size_t)b * TT * HH;        // + kt*4096 + cc*8
    const u16* vbase = vp + (size_t)b * 64 * 64 * 64;   // + kt*4096 + cc*8

    f32x4 zero = {0.f, 0.f, 0.f, 0.f};
    f32x4 oA[4], oB[4];
    #pragma unroll
    for (int i = 0; i < 4; i++) { oA[i] = zero; oB[i] = zero; }
    float lsumA = 0.f, lsumB = 0.f;

    const int nstep = (qtA - ks) / nsplit + 1;   // >= 8 (qtA>=32, ks<=3)

    // prologue: stage tile t0 into buf0; prefetch t1 into regs
    uint4 rk0, rk1, rv0, rv1;
    {
        size_t t0 = (size_t)ks * 4096;
        rk0 = *reinterpret_cast<const uint4*>(kbase + t0 + cc0 * 8);
        rk1 = *reinterpret_cast<const uint4*>(kbase + t0 + cc1 * 8);
        rv0 = *reinterpret_cast<const uint4*>(vbase + t0 + cc0 * 8);
        rv1 = *reinterpret_cast<const uint4*>(vbase + t0 + cc1 * 8);
    }
    *reinterpret_cast<uint4*>(&kst[0][dst0]) = rk0;
    *reinterpret_cast<uint4*>(&kst[0][dst1]) = rk1;
    *reinterpret_cast<uint4*>(&vts[0][dst0]) = rv0;
    *reinterpret_cast<uint4*>(&vts[0][dst1]) = rv1;
    if (nstep > 1) {
        size_t t1 = (size_t)(ks + nsplit) * 4096;
        rk0 = *reinterpret_cast<const uint4*>(kbase + t1 + cc0 * 8);
        rk1 = *reinterpret_cast<const uint4*>(kbase + t1 + cc1 * 8);
        rv0 = *reinterpret_cast<const uint4*>(vbase + t1 + cc0 * 8);
        rv1 = *reinterpret_cast<const uint4*>(vbase + t1 + cc1 * 8);
    }

    for (int j = 0; j < nstep; ++j) {
        __syncthreads();              // separates buf[cur] writes(j-1)/reads(j) AND buf[cur^1] reads(j-1)/writes(j)
        const int cur = j & 1;
        if (j + 1 < nstep) {          // write NEXT tile's buffer from regs
            *reinterpret_cast<uint4*>(&kst[cur ^ 1][dst0]) = rk0;
            *reinterpret_cast<uint4*>(&kst[cur ^ 1][dst1]) = rk1;
            *reinterpret_cast<uint4*>(&vts[cur ^ 1][dst0]) = rv0;
            *reinterpret_cast<uint4*>(&vts[cur ^ 1][dst1]) = rv1;
        }
        if (j + 2 < nstep) {          // issue loads for tile t_{j+2}; fly under compute
            size_t tn = (size_t)(ks + (j + 2) * nsplit) * 4096;
            rk0 = *reinterpret_cast<const uint4*>(kbase + tn + cc0 * 8);
            rk1 = *reinterpret_cast<const uint4*>(kbase + tn + cc1 * 8);
            rv0 = *reinterpret_cast<const uint4*>(vbase + tn + cc0 * 8);
            rv1 = *reinterpret_cast<const uint4*>(vbase + tn + cc1 * 8);
        }
        const int kt = ks + j * nsplit;

        f32x4 sA[4];
        #pragma unroll
        for (int i = 0; i < 4; i++) sA[i] = zero;
        qkt(&kst[cur][0], aqA, sA, l15, quad);
        short8 bpA[2];
        sm_pack(sA, bpA, lsumA, kt, q_gA, kt == qtA, l15, quad);
        pv_reg(&vts[cur][0], bpA, oA, l15, quad);

        if (kt <= qtB) {
            f32x4 sB[4];
            #pragma unroll
            for (int i = 0; i < 4; i++) sB[i] = zero;
            qkt(&kst[cur][0], aqB, sB, l15, quad);
            short8 bpB[2];
            sm_pack(sB, bpB, lsumB, kt, q_gB, kt == qtB, l15, quad);
            pv_reg(&vts[cur][0], bpB, oB, l15, quad);
        }
    }

    // denom: sum the 4 quads' partials (q fixed per thread at l15)
    lsumA += __shfl_xor(lsumA, 16);
    lsumA += __shfl_xor(lsumA, 32);
    lsumB += __shfl_xor(lsumB, 16);
    lsumB += __shfl_xor(lsumB, 32);

    const size_t g0qA = (size_t)(b * TT) + q_gA;
    const size_t g0qB = (size_t)(b * TT) + q_gB;

    if (nsplit == 1) {
        float invA = 1.0f / lsumA;
        float invB = 1.0f / lsumB;
        if (isbf) {
            u16* outp = (u16*)outv;
            #pragma unroll
            for (int nt = 0; nt < 4; nt++) {
                ushort4 sa, sb;
                sa.x = f2bf(oA[nt][0] * invA); sa.y = f2bf(oA[nt][1] * invA);
                sa.z = f2bf(oA[nt][2] * invA); sa.w = f2bf(oA[nt][3] * invA);
                sb.x = f2bf(oB[nt][0] * invB); sb.y = f2bf(oB[nt][1] * invB);
                sb.z = f2bf(oB[nt][2] * invB); sb.w = f2bf(oB[nt][3] * invB);
                *reinterpret_cast<ushort4*>(outp + g0qA * HH + nt * 16 + quad * 4) = sa;
                *reinterpret_cast<ushort4*>(outp + g0qB * HH + nt * 16 + quad * 4) = sb;
            }
        } else {
            float* outp = (float*)outv;
            #pragma unroll
            for (int nt = 0; nt < 4; nt++) {
                float4 sa = {oA[nt][0] * invA, oA[nt][1] * invA, oA[nt][2] * invA, oA[nt][3] * invA};
                float4 sb = {oB[nt][0] * invB, oB[nt][1] * invB, oB[nt][2] * invB, oB[nt][3] * invB};
                *reinterpret_cast<float4*>(outp + g0qA * HH + nt * 16 + quad * 4) = sa;
                *reinterpret_cast<float4*>(outp + g0qB * HH + nt * 16 + quad * 4) = sb;
            }
        }
    } else {
        // slot-based partial writes: (b,qt,ks) owns distinct rows of slot ks
        float* accos = acco + (size_t)ks * (BB * TT * HH);
        float* accls = accl + (size_t)ks * (BB * TT);
        #pragma unroll
        for (int nt = 0; nt < 4; nt++) {
            float4 sv = {oA[nt][0], oA[nt][1], oA[nt][2], oA[nt][3]};
            *reinterpret_cast<float4*>(accos + g0qA * HH + nt * 16 + quad * 4) = sv;
        }
        if (quad == 0) accls[g0qA] = lsumA;
        if (ks <= qtB) {
            #pragma unroll
            for (int nt = 0; nt < 4; nt++) {
                float4 sv = {oB[nt][0], oB[nt][1], oB[nt][2], oB[nt][3]};
                *reinterpret_cast<float4*>(accos + g0qB * HH + nt * 16 + quad * 4) = sv;
            }
            if (quad == 0) accls[g0qB] = lsumB;
        }
    }
}

// ---------------- finalize: out = (sum over active slots of acco) / (sum accl)
__global__ __launch_bounds__(256) void attn_finalize(const float* __restrict__ acco,
                                                     const float* __restrict__ accl,
                                                     void* __restrict__ outv,
                                                     const int* __restrict__ flag, int nsplit) {
    const int isbf = *flag;
    int i = blockIdx.x * blockDim.x + threadIdx.x;   // float4 index over B*T*H
    int row = i >> 4;
    int qt = (row & (TT - 1)) >> 6;
    int nact = min(nsplit, qt + 1);
    float4 ov = reinterpret_cast<const float4*>(acco)[i];
    float l = accl[row];
    for (int s = 1; s < nact; s++) {
        float4 t = reinterpret_cast<const float4*>(acco + (size_t)s * (BB * TT * HH))[i];
        ov.x += t.x; ov.y += t.y; ov.z += t.z; ov.w += t.w;
        l += accl[(size_t)s * (BB * TT) + row];
    }
    float inv = 1.0f / l;
    if (isbf) {
        ushort4 s;
        s.x = f2bf(ov.x * inv); s.y = f2bf(ov.y * inv);
        s.z = f2bf(ov.z * inv); s.w = f2bf(ov.w * inv);
        reinterpret_cast<ushort4*>(outv)[i] = s;
    } else {
        float4 s = {ov.x * inv, ov.y * inv, ov.z * inv, ov.w * inv};
        reinterpret_cast<float4*>(outv)[i] = s;
    }
}

extern "C" void kernel_launch(void* const* d_in, const int* in_sizes, int n_in,
                              void* d_out, int out_size, void* d_ws, size_t ws_size,
                              hipStream_t stream) {
    const void* x  = d_in[0];
    const void* Wk = d_in[1];
    const void* Wq = d_in[2];
    const void* Wv = d_in[3];
    char* ws = (char*)d_ws;
    // ws: qo 0-2M | ko 2-4M | vo 4-6M | Wtp @6M(384K) | flag @6.75M
    //     acco @7M (4 slots x 4M) | accl @39M (4 slots x 64K)
    u16* qo = (u16*)(ws);
    u16* ko = (u16*)(ws + (size_t)2 * 1024 * 1024);
    u16* vo = (u16*)(ws + (size_t)4 * 1024 * 1024);
    u16* Wtp = (u16*)(ws + (size_t)6 * 1024 * 1024);
    int* flag = (int*)(ws + (size_t)6 * 1024 * 1024 + 768 * 1024);
    float* acco = (float*)(ws + (size_t)7 * 1024 * 1024);
    float* accl = (float*)(ws + (size_t)39 * 1024 * 1024);

    const size_t need_split = (size_t)40 * 1024 * 1024;
    const int nsplit = (ws_size >= need_split) ? 4 : 1;

    prep<<<192, 256, 0, stream>>>(Wk, Wq, Wv, (const u16*)x, Wtp, flag);
    qkv_proj<<<512, 256, 0, stream>>>(x, Wtp, qo, ko, vo, flag);
    attn<<<BB * 32 * nsplit, 256, 0, stream>>>(qo, ko, vo, acco, accl, d_out, flag, nsplit);
    if (nsplit > 1) {
        attn_finalize<<<(BB * TT * HH / 4) / 256, 256, 0, stream>>>(acco, accl, d_out, flag, nsplit);
    }
}